// Round 10
// baseline (447.325 us; speedup 1.0000x reference)
//
#include <hip/hip_runtime.h>

#define S_LEN 2048
#define BATCH 16
#define DIM   512
#define KVB   64
#define NT    (S_LEN / KVB)   // 32

typedef __bf16 bf16x8 __attribute__((ext_vector_type(8)));
typedef float  f32x4  __attribute__((ext_vector_type(4)));
typedef float  f32x16 __attribute__((ext_vector_type(16)));
typedef unsigned int u32x4 __attribute__((ext_vector_type(4)));

static __device__ __forceinline__ unsigned short f2bf(float f) {
    __bf16 h = (__bf16)f;
    return __builtin_bit_cast(unsigned short, h);
}
static __device__ __forceinline__ bf16x8 ld_bf8(const unsigned short* p) {
    u32x4 v = *reinterpret_cast<const u32x4*>(p);
    return __builtin_bit_cast(bf16x8, v);
}
static __device__ __forceinline__ f32x4 mfma16(bf16x8 a, bf16x8 b, f32x4 c) {
    return __builtin_amdgcn_mfma_f32_16x16x32_bf16(a, b, c, 0, 0, 0);
}
static __device__ __forceinline__ f32x16 mfma32(bf16x8 a, bf16x8 b, f32x16 c) {
    return __builtin_amdgcn_mfma_f32_32x32x16_bf16(a, b, c, 0, 0, 0);
}
static __device__ __forceinline__ void gload16(const unsigned short* g, unsigned short* l) {
    __builtin_amdgcn_global_load_lds(
        (const __attribute__((address_space(1))) unsigned int*)g,
        (__attribute__((address_space(3))) unsigned int*)l, 16, 0, 0);
}
#define WAITV(N) do { asm volatile("s_waitcnt vmcnt(" #N ")" ::: "memory"); \
                      __builtin_amdgcn_sched_barrier(0); } while (0)
static __device__ __forceinline__ void waitlg0() {
    asm volatile("s_waitcnt lgkmcnt(0)" ::: "memory");
    __builtin_amdgcn_sched_barrier(0);
}

// ---- pack_seq: seq [S][B][D] f32 -> seqb frag tiles [B][S/16][D/32][16][32]
//                                  -> vt2  frag tiles [B][S/16][D/32][32][16]
__global__ void pack_seq(const float* __restrict__ seq, unsigned short* __restrict__ seqb,
                         unsigned short* __restrict__ vt) {
    __shared__ float tile[32][33];
    int b  = blockIdx.z;
    int d0 = blockIdx.y * 32;
    int s0 = blockIdx.x * 32;
    int t  = threadIdx.x;
    {
        int sl = t >> 3, c4 = (t & 7) * 4;
        float4 v = *reinterpret_cast<const float4*>(
            seq + (size_t)(s0 + sl) * (BATCH * DIM) + (size_t)b * DIM + d0 + c4);
        tile[sl][c4 + 0] = v.x; tile[sl][c4 + 1] = v.y;
        tile[sl][c4 + 2] = v.z; tile[sl][c4 + 3] = v.w;
        uint2 r;
        r.x = (unsigned)f2bf(v.x) | ((unsigned)f2bf(v.y) << 16);
        r.y = (unsigned)f2bf(v.z) | ((unsigned)f2bf(v.w) << 16);
        int s = s0 + sl, d = d0 + c4;
        size_t off = ((size_t)(b * 128 + (s >> 4)) * 16 + (d >> 5)) * 512
                     + (s & 15) * 32 + (d & 31);
        *reinterpret_cast<uint2*>(seqb + off) = r;
    }
    __syncthreads();
    {
        int dl = t >> 3, s4 = (t & 7) * 4;
        uint2 r;
        r.x = (unsigned)f2bf(tile[s4 + 0][dl]) | ((unsigned)f2bf(tile[s4 + 1][dl]) << 16);
        r.y = (unsigned)f2bf(tile[s4 + 2][dl]) | ((unsigned)f2bf(tile[s4 + 3][dl]) << 16);
        int d = d0 + dl, s = s0 + s4;
        size_t off = ((size_t)(b * 128 + (s >> 4)) * 16 + (d >> 5)) * 512
                     + (d & 31) * 16 + (s & 15);
        *reinterpret_cast<uint2*>(vt + off) = r;
    }
}

// ---- fallback pack (vt2 only, when ws too small for seqb) ----
__global__ void pack_vt(const float* __restrict__ seq, unsigned short* __restrict__ vt) {
    __shared__ float tile[32][33];
    int b  = blockIdx.z;
    int d0 = blockIdx.y * 32;
    int s0 = blockIdx.x * 32;
    int t  = threadIdx.x;
    {
        int sl = t >> 3, c4 = (t & 7) * 4;
        float4 v = *reinterpret_cast<const float4*>(
            seq + (size_t)(s0 + sl) * (BATCH * DIM) + (size_t)b * DIM + d0 + c4);
        tile[sl][c4 + 0] = v.x; tile[sl][c4 + 1] = v.y;
        tile[sl][c4 + 2] = v.z; tile[sl][c4 + 3] = v.w;
    }
    __syncthreads();
    {
        int dl = t >> 3, s4 = (t & 7) * 4;
        uint2 r;
        r.x = (unsigned)f2bf(tile[s4 + 0][dl]) | ((unsigned)f2bf(tile[s4 + 1][dl]) << 16);
        r.y = (unsigned)f2bf(tile[s4 + 2][dl]) | ((unsigned)f2bf(tile[s4 + 3][dl]) << 16);
        int d = d0 + dl, s = s0 + s4;
        size_t off = ((size_t)(b * 128 + (s >> 4)) * 16 + (d >> 5)) * 512
                     + (d & 31) * 16 + (s & 15);
        *reinterpret_cast<uint2*>(vt + off) = r;
    }
}

// -------- value = tanh(seq_in @ Wv^T + bv) -> bf16 fragment tiles --------
// val2 layout: [B][S/16][D/32][16][32]; tile elem (srow, dcol) at srow*32+dcol
template <bool BF16A>
__global__ void __launch_bounds__(256) gemm_value(
        const float* __restrict__ seq, const unsigned short* __restrict__ seqb,
        const float* __restrict__ wv, const float* __restrict__ bv,
        unsigned short* __restrict__ val) {
    __shared__ unsigned short Asm[64][72];
    __shared__ unsigned short Bsm[64][72];
    int t  = threadIdx.x;
    int rb = blockIdx.x * 64;
    int cb = blockIdx.y * 64;
    int w = t >> 6, l = t & 63;
    int mi = w >> 1, ni = w & 1;
    int l15 = l & 15, lh = l >> 4;
    f32x4 acc[2][2] = {};

    int srow = t >> 2;
    int qc   = (t & 3) * 16;
    int gr = rb + srow;
    int sb = gr >> 11, ss = gr & 2047;
    const float* aSrc = seq + ((size_t)ss * BATCH + sb) * DIM + qc;
    const float* bSrc = wv + (size_t)(cb + srow) * DIM + qc;

    for (int k0 = 0; k0 < DIM; k0 += 64) {
        if (BF16A) {
            int dcol = k0 + qc;
            const unsigned short* p = seqb
                + ((size_t)(sb * 128 + (ss >> 4)) * 16 + (dcol >> 5)) * 512
                + (ss & 15) * 32 + (dcol & 31);
            *reinterpret_cast<u32x4*>(&Asm[srow][qc])     = *reinterpret_cast<const u32x4*>(p);
            *reinterpret_cast<u32x4*>(&Asm[srow][qc + 8]) = *reinterpret_cast<const u32x4*>(p + 8);
        } else {
            unsigned short ar[16];
            #pragma unroll
            for (int j = 0; j < 4; ++j) {
                float4 v = *reinterpret_cast<const float4*>(aSrc + k0 + j * 4);
                ar[j * 4 + 0] = f2bf(v.x); ar[j * 4 + 1] = f2bf(v.y);
                ar[j * 4 + 2] = f2bf(v.z); ar[j * 4 + 3] = f2bf(v.w);
            }
            *reinterpret_cast<u32x4*>(&Asm[srow][qc])     = *reinterpret_cast<u32x4*>(&ar[0]);
            *reinterpret_cast<u32x4*>(&Asm[srow][qc + 8]) = *reinterpret_cast<u32x4*>(&ar[8]);
        }
        {
            unsigned short br[16];
            #pragma unroll
            for (int j = 0; j < 4; ++j) {
                float4 u = *reinterpret_cast<const float4*>(bSrc + k0 + j * 4);
                br[j * 4 + 0] = f2bf(u.x); br[j * 4 + 1] = f2bf(u.y);
                br[j * 4 + 2] = f2bf(u.z); br[j * 4 + 3] = f2bf(u.w);
            }
            *reinterpret_cast<u32x4*>(&Bsm[srow][qc])     = *reinterpret_cast<u32x4*>(&br[0]);
            *reinterpret_cast<u32x4*>(&Bsm[srow][qc + 8]) = *reinterpret_cast<u32x4*>(&br[8]);
        }
        __syncthreads();
        #pragma unroll
        for (int kf = 0; kf < 2; ++kf) {
            bf16x8 af[2], bfm[2];
            #pragma unroll
            for (int i = 0; i < 2; ++i)
                af[i] = ld_bf8(&Asm[mi * 32 + i * 16 + l15][kf * 32 + lh * 8]);
            #pragma unroll
            for (int j = 0; j < 2; ++j)
                bfm[j] = ld_bf8(&Bsm[ni * 32 + j * 16 + l15][kf * 32 + lh * 8]);
            #pragma unroll
            for (int i = 0; i < 2; ++i)
                #pragma unroll
                for (int j = 0; j < 2; ++j)
                    acc[i][j] = mfma16(af[i], bfm[j], acc[i][j]);
        }
        __syncthreads();
    }
    #pragma unroll
    for (int i = 0; i < 2; ++i) {
        #pragma unroll
        for (int j = 0; j < 2; ++j) {
            int gcol = cb + ni * 32 + j * 16 + l15;
            float bias = bv[gcol];
            #pragma unroll
            for (int r = 0; r < 4; ++r) {
                int grow = rb + mi * 32 + i * 16 + lh * 4 + r;
                float x = acc[i][j][r] + bias;
                int b_ = grow >> 11, s_ = grow & 2047;
                size_t off = ((size_t)(b_ * 128 + (s_ >> 4)) * 16 + (gcol >> 5)) * 512
                             + (s_ & 15) * 32 + (gcol & 31);
                val[off] = f2bf(tanhf(x));
            }
        }
    }
}

// ---------------- fused flash attention v10 ----------------
// R9 lane-major frag LDS + Q-doubling: QK roles (qi2 in {0,1} x kv4 in {0..3}),
// qf[2][16] = 128 VGPR, each wave reads ONLY its 16-kv quarter of K -> K LDS
// read amp 4x -> 2x (256->128 KB/iter). PV roles dq in 0..7 (V amp 1x).
// Schedule, PS skew, counted vmcnt(8), defer-max THR=8: identical to R9.
__global__ void __launch_bounds__(512, 2) attn_fused(
        const unsigned short* __restrict__ val, const unsigned short* __restrict__ vt,
        float* __restrict__ out) {
    extern __shared__ char smem[];
    unsigned short* Kb = (unsigned short*)smem;              // 64 frags x 1KB lane-major
    unsigned short* Vb = (unsigned short*)(smem + 65536);    // 64 frags x 1KB lane-major
    float*          Sb = (float*)(smem + 131072);            // [64][68] f32
    unsigned short* PS = (unsigned short*)(smem + 148480);   // 8 frags x 1KB + skew
    float* stm = (float*)(smem + 156928);                    // [64]
    float* stl = stm + 64;
    float* sts = stm + 128;

    const int t = threadIdx.x;
    const int w = t >> 6, l = t & 63;
    const int l15 = l & 15, lh = l >> 4;
    const int l31 = l & 31, lh1 = l >> 5;

    int wg  = blockIdx.x;
    int swz = (wg & 7) * 64 + (wg >> 3);     // XCD-chunked, bijective (512 = 8*64)
    int b   = swz >> 5;
    int qb  = (swz & 31) * 64;

    const int qi2 = w >> 2, kv4 = w & 3;     // QK: S[qi2*32..+32][kv4*16..+16]
    const int dq = w;                        // PV: O[64q][dq*64..+64]

    const unsigned short* valb = val + (size_t)b * 128 * 16 * 512;
    const unsigned short* vtb  = vt  + (size_t)b * 128 * 16 * 512;

    if (t < 64) { stm[t] = -3.0e38f; stl[t] = 0.0f; }

    // Q fragments: 32 q rows (2 s16-tiles), 16 d32 ksteps (128 VGPR)
    bf16x8 qf[2][16];
    {
        const unsigned short* qp = valb + ((size_t)((qb >> 4) + qi2 * 2) * 16) * 512
                                   + l15 * 32 + lh * 8;
        #pragma unroll
        for (int m = 0; m < 2; ++m)
            #pragma unroll
            for (int ks = 0; ks < 16; ++ks)
                qf[m][ks] = ld_bf8(qp + (size_t)(m * 16 + ks) * 512);
    }
    f32x16 o[4] = {};   // [qg*2+dtl]: 64q x 64d

    // Kb frag (g,ks): lane l holds K[kv = g*16 + (l&15)][d = ks*32 + (l>>4)*8 ..+8]
    auto dmaK = [&](int kt) {
        #pragma unroll
        for (int i = 0; i < 8; ++i) {
            int idx = i * 8 + w, g = idx >> 4, ks = idx & 15;
            gload16(valb + ((size_t)(kt * 4 + g) * 16 + ks) * 512 + l15 * 32 + lh * 8,
                    Kb + idx * 512);
        }
    };
    // Vb frag (ks,dt): lane l holds V[kv = ks*16 + (l>>5)*8 ..+8][d = dt*32 + (l&31)]
    auto dmaV = [&](int kt) {
        #pragma unroll
        for (int i = 0; i < 8; ++i) {
            int idx = i * 8 + w, ks = idx >> 4, dt = idx & 15;
            gload16(vtb + ((size_t)(kt * 4 + ks) * 16 + dt) * 512 + l31 * 16 + lh1 * 8,
                    Vb + idx * 512);
        }
    };

    // ---- prologue: K(0), V(0); drain everything (incl. qf loads) ----
    dmaK(0);
    dmaV(0);
    WAITV(0);
    __builtin_amdgcn_s_barrier();

    for (int kt = 0; kt < NT; ++kt) {
        // ---- phase A: QK(kt) ----
        WAITV(8);                               // retire K(kt) (V stays in flight)
        __builtin_amdgcn_s_barrier();
        {
            const unsigned short* kb = Kb + (size_t)kv4 * 16 * 512 + l * 8;
            f32x4 a0 = {}, a1 = {};
            __builtin_amdgcn_s_setprio(1);
            #pragma unroll
            for (int ks = 0; ks < 16; ++ks) {
                bf16x8 kf = ld_bf8(kb + ks * 512);
                a0 = mfma16(qf[0][ks], kf, a0);
                a1 = mfma16(qf[1][ks], kf, a1);
            }
            __builtin_amdgcn_s_setprio(0);
            #pragma unroll
            for (int r = 0; r < 4; ++r) {
                Sb[(qi2 * 32 + lh * 4 + r) * 68 + kv4 * 16 + l15]      = a0[r];
                Sb[(qi2 * 32 + 16 + lh * 4 + r) * 68 + kv4 * 16 + l15] = a1[r];
            }
        }
        waitlg0();
        __builtin_amdgcn_s_barrier();

        // ---- phase B: issue K(kt+1); softmax(kt) -> PS; retire V(kt) ----
        {
            int nk = (kt + 1 < NT) ? kt + 1 : NT - 1;
            dmaK(nk);
        }
        {
            int row = t >> 3, e = t & 7;
            const float* sp = Sb + row * 68 + e * 8;
            f32x4 x0 = *reinterpret_cast<const f32x4*>(sp);
            f32x4 x1 = *reinterpret_cast<const f32x4*>(sp + 4);
            float mt = fmaxf(fmaxf(fmaxf(x0[0], x0[1]), fmaxf(x0[2], x0[3])),
                             fmaxf(fmaxf(x1[0], x1[1]), fmaxf(x1[2], x1[3])));
            #pragma unroll
            for (int m = 1; m <= 4; m <<= 1) mt = fmaxf(mt, __shfl_xor(mt, m, 64));
            float m_old = stm[row];
            float m_new = (mt > m_old + 8.0f) ? mt : m_old;    // defer-max THR=8
            float e0 = __expf(x0[0] - m_new), e1 = __expf(x0[1] - m_new);
            float e2 = __expf(x0[2] - m_new), e3 = __expf(x0[3] - m_new);
            float e4 = __expf(x1[0] - m_new), e5 = __expf(x1[1] - m_new);
            float e6 = __expf(x1[2] - m_new), e7 = __expf(x1[3] - m_new);
            float lt = ((e0 + e1) + (e2 + e3)) + ((e4 + e5) + (e6 + e7));
            #pragma unroll
            for (int m = 1; m <= 4; m <<= 1) lt += __shfl_xor(lt, m, 64);
            u32x4 pk;
            pk[0] = (unsigned)f2bf(e0) | ((unsigned)f2bf(e1) << 16);
            pk[1] = (unsigned)f2bf(e2) | ((unsigned)f2bf(e3) << 16);
            pk[2] = (unsigned)f2bf(e4) | ((unsigned)f2bf(e5) << 16);
            pk[3] = (unsigned)f2bf(e6) | ((unsigned)f2bf(e7) << 16);
            // PS frag (qg=row>>5, ks=e>>1), slot = (e&1)*32 + (row&31), skew ks*8
            int ks = e >> 1, qg = row >> 5;
            unsigned short* pdst = PS + ((qg * 4 + ks) * 512 + ks * 8)
                                   + ((e & 1) * 32 + (row & 31)) * 8;
            *reinterpret_cast<u32x4*>(pdst) = pk;
            if (e == 0) {
                float alpha = (m_new == m_old) ? 1.0f : __expf(m_old - m_new);
                sts[row] = alpha;
                stm[row] = m_new;
                stl[row] = stl[row] * alpha + lt;
            }
        }
        waitlg0();
        WAITV(8);                               // retire V(kt) (K(kt+1) stays)
        __builtin_amdgcn_s_barrier();

        // ---- phase C: rescale O + PV(kt) ----
        {
            f32x4 al[2][4];
            bool need = false;
            #pragma unroll
            for (int qg = 0; qg < 2; ++qg)
                #pragma unroll
                for (int c = 0; c < 4; ++c) {
                    al[qg][c] = *reinterpret_cast<const f32x4*>(
                        sts + qg * 32 + 4 * lh1 + 8 * c);
                    #pragma unroll
                    for (int j = 0; j < 4; ++j) need = need || (al[qg][c][j] != 1.0f);
                }
            if (__any((int)need)) {
                #pragma unroll
                for (int qg = 0; qg < 2; ++qg)
                    #pragma unroll
                    for (int dtl = 0; dtl < 2; ++dtl)
                        #pragma unroll
                        for (int rr = 0; rr < 16; ++rr)
                            o[qg * 2 + dtl][rr] *= al[qg][rr >> 2][rr & 3];
            }
            __builtin_amdgcn_s_setprio(1);
            #pragma unroll
            for (int ks = 0; ks < 4; ++ks) {
                bf16x8 pa0 = ld_bf8(PS + ((0 + ks) * 512 + ks * 8) + l * 8);
                bf16x8 pa1 = ld_bf8(PS + ((4 + ks) * 512 + ks * 8) + l * 8);
                #pragma unroll
                for (int dtl = 0; dtl < 2; ++dtl) {
                    bf16x8 vf = ld_bf8(Vb + (size_t)(ks * 16 + dq * 2 + dtl) * 512 + l * 8);
                    o[0 + dtl] = mfma32(pa0, vf, o[0 + dtl]);
                    o[2 + dtl] = mfma32(pa1, vf, o[2 + dtl]);
                }
            }
            __builtin_amdgcn_s_setprio(0);
        }
        waitlg0();
        __builtin_amdgcn_s_barrier();           // all PV reads of V(kt) done
        {
            int nv = (kt + 1 < NT) ? kt + 1 : NT - 1;
            dmaV(nv);                           // safe: after barrier
        }
    }

    // ---- epilogue ----
    #pragma unroll
    for (int qg = 0; qg < 2; ++qg) {
        f32x4 li[4];
        #pragma unroll
        for (int c = 0; c < 4; ++c) {
            f32x4 lv = *reinterpret_cast<const f32x4*>(stl + qg * 32 + 4 * lh1 + 8 * c);
            #pragma unroll
            for (int j = 0; j < 4; ++j) li[c][j] = 1.0f / lv[j];
        }
        #pragma unroll
        for (int dtl = 0; dtl < 2; ++dtl) {
            int col = dq * 64 + dtl * 32 + l31;
            #pragma unroll
            for (int rr = 0; rr < 16; ++rr) {
                int cr  = (rr & 3) + 8 * (rr >> 2) + 4 * lh1;
                int row = qb + qg * 32 + cr;
                out[(size_t)row * (BATCH * DIM) + (size_t)b * DIM + col] =
                    o[qg * 2 + dtl][rr] * li[rr >> 2][rr & 3];
            }
        }
    }
}

extern "C" void kernel_launch(void* const* d_in, const int* in_sizes, int n_in,
                              void* d_out, int out_size, void* d_ws, size_t ws_size,
                              hipStream_t stream) {
    const float* seq = (const float*)d_in[0];   // [S][B][D] f32
    const float* wv  = (const float*)d_in[1];   // [D][D] f32
    const float* bv  = (const float*)d_in[2];   // [D] f32
    float* outp = (float*)d_out;                // [S][B][D] f32

    unsigned short* wsVal  = (unsigned short*)d_ws;                         // 32 MB
    unsigned short* wsVt   = (unsigned short*)((char*)d_ws + 33554432);     // 32 MB
    unsigned short* wsSeqb = (unsigned short*)((char*)d_ws + 67108864);     // 32 MB

    bool fused = ws_size >= 100663296ull;   // need 96 MB for seqb path
    if (fused) {
        pack_seq<<<dim3(S_LEN / 32, DIM / 32, BATCH), dim3(256), 0, stream>>>(
            seq, wsSeqb, wsVt);
        gemm_value<true><<<dim3(BATCH * S_LEN / 64, DIM / 64), dim3(256), 0, stream>>>(
            seq, wsSeqb, wv, bv, wsVal);
    } else {
        pack_vt<<<dim3(S_LEN / 32, DIM / 32, BATCH), dim3(256), 0, stream>>>(seq, wsVt);
        gemm_value<false><<<dim3(BATCH * S_LEN / 64, DIM / 64), dim3(256), 0, stream>>>(
            seq, nullptr, wv, bv, wsVal);
    }
    attn_fused<<<dim3(512), dim3(512), 157696, stream>>>(wsVal, wsVt, outp);
}

// Round 11
// 446.281 us; speedup vs baseline: 1.0023x; 1.0023x over previous
//
#include <hip/hip_runtime.h>

#define S_LEN 2048
#define BATCH 16
#define DIM   512
#define KVB   64
#define NT    (S_LEN / KVB)   // 32

typedef __bf16 bf16x8 __attribute__((ext_vector_type(8)));
typedef float  f32x4  __attribute__((ext_vector_type(4)));
typedef float  f32x16 __attribute__((ext_vector_type(16)));
typedef unsigned int u32x4 __attribute__((ext_vector_type(4)));

static __device__ __forceinline__ unsigned short f2bf(float f) {
    __bf16 h = (__bf16)f;
    return __builtin_bit_cast(unsigned short, h);
}
static __device__ __forceinline__ bf16x8 ld_bf8(const unsigned short* p) {
    u32x4 v = *reinterpret_cast<const u32x4*>(p);
    return __builtin_bit_cast(bf16x8, v);
}
static __device__ __forceinline__ f32x4 mfma16(bf16x8 a, bf16x8 b, f32x4 c) {
    return __builtin_amdgcn_mfma_f32_16x16x32_bf16(a, b, c, 0, 0, 0);
}
static __device__ __forceinline__ f32x16 mfma32(bf16x8 a, bf16x8 b, f32x16 c) {
    return __builtin_amdgcn_mfma_f32_32x32x16_bf16(a, b, c, 0, 0, 0);
}
static __device__ __forceinline__ void gload16(const unsigned short* g, unsigned short* l) {
    __builtin_amdgcn_global_load_lds(
        (const __attribute__((address_space(1))) unsigned int*)g,
        (__attribute__((address_space(3))) unsigned int*)l, 16, 0, 0);
}
#define WAITV(N) do { asm volatile("s_waitcnt vmcnt(" #N ")" ::: "memory"); \
                      __builtin_amdgcn_sched_barrier(0); } while (0)
static __device__ __forceinline__ void waitlg0() {
    asm volatile("s_waitcnt lgkmcnt(0)" ::: "memory");
    __builtin_amdgcn_sched_barrier(0);
}

// ---- pack_seq: seq [S][B][D] f32 -> seqb frag tiles [B][S/16][D/32][16][32]
//                                  -> vt2  frag tiles [B][S/16][D/32][32][16]
__global__ void pack_seq(const float* __restrict__ seq, unsigned short* __restrict__ seqb,
                         unsigned short* __restrict__ vt) {
    __shared__ float tile[32][33];
    int b  = blockIdx.z;
    int d0 = blockIdx.y * 32;
    int s0 = blockIdx.x * 32;
    int t  = threadIdx.x;
    {
        int sl = t >> 3, c4 = (t & 7) * 4;
        float4 v = *reinterpret_cast<const float4*>(
            seq + (size_t)(s0 + sl) * (BATCH * DIM) + (size_t)b * DIM + d0 + c4);
        tile[sl][c4 + 0] = v.x; tile[sl][c4 + 1] = v.y;
        tile[sl][c4 + 2] = v.z; tile[sl][c4 + 3] = v.w;
        uint2 r;
        r.x = (unsigned)f2bf(v.x) | ((unsigned)f2bf(v.y) << 16);
        r.y = (unsigned)f2bf(v.z) | ((unsigned)f2bf(v.w) << 16);
        int s = s0 + sl, d = d0 + c4;
        size_t off = ((size_t)(b * 128 + (s >> 4)) * 16 + (d >> 5)) * 512
                     + (s & 15) * 32 + (d & 31);
        *reinterpret_cast<uint2*>(seqb + off) = r;
    }
    __syncthreads();
    {
        int dl = t >> 3, s4 = (t & 7) * 4;
        uint2 r;
        r.x = (unsigned)f2bf(tile[s4 + 0][dl]) | ((unsigned)f2bf(tile[s4 + 1][dl]) << 16);
        r.y = (unsigned)f2bf(tile[s4 + 2][dl]) | ((unsigned)f2bf(tile[s4 + 3][dl]) << 16);
        int d = d0 + dl, s = s0 + s4;
        size_t off = ((size_t)(b * 128 + (s >> 4)) * 16 + (d >> 5)) * 512
                     + (d & 31) * 16 + (s & 15);
        *reinterpret_cast<uint2*>(vt + off) = r;
    }
}

// ---- fallback pack (vt2 only, when ws too small for seqb) ----
__global__ void pack_vt(const float* __restrict__ seq, unsigned short* __restrict__ vt) {
    __shared__ float tile[32][33];
    int b  = blockIdx.z;
    int d0 = blockIdx.y * 32;
    int s0 = blockIdx.x * 32;
    int t  = threadIdx.x;
    {
        int sl = t >> 3, c4 = (t & 7) * 4;
        float4 v = *reinterpret_cast<const float4*>(
            seq + (size_t)(s0 + sl) * (BATCH * DIM) + (size_t)b * DIM + d0 + c4);
        tile[sl][c4 + 0] = v.x; tile[sl][c4 + 1] = v.y;
        tile[sl][c4 + 2] = v.z; tile[sl][c4 + 3] = v.w;
    }
    __syncthreads();
    {
        int dl = t >> 3, s4 = (t & 7) * 4;
        uint2 r;
        r.x = (unsigned)f2bf(tile[s4 + 0][dl]) | ((unsigned)f2bf(tile[s4 + 1][dl]) << 16);
        r.y = (unsigned)f2bf(tile[s4 + 2][dl]) | ((unsigned)f2bf(tile[s4 + 3][dl]) << 16);
        int d = d0 + dl, s = s0 + s4;
        size_t off = ((size_t)(b * 128 + (s >> 4)) * 16 + (d >> 5)) * 512
                     + (d & 31) * 16 + (s & 15);
        *reinterpret_cast<uint2*>(vt + off) = r;
    }
}

// -------- value = tanh(seq_in @ Wv^T + bv) -> bf16 fragment tiles --------
// val2 layout: [B][S/16][D/32][16][32]; tile elem (srow, dcol) at srow*32+dcol
template <bool BF16A>
__global__ void __launch_bounds__(256) gemm_value(
        const float* __restrict__ seq, const unsigned short* __restrict__ seqb,
        const float* __restrict__ wv, const float* __restrict__ bv,
        unsigned short* __restrict__ val) {
    __shared__ unsigned short Asm[64][72];
    __shared__ unsigned short Bsm[64][72];
    int t  = threadIdx.x;
    int rb = blockIdx.x * 64;
    int cb = blockIdx.y * 64;
    int w = t >> 6, l = t & 63;
    int mi = w >> 1, ni = w & 1;
    int l15 = l & 15, lh = l >> 4;
    f32x4 acc[2][2] = {};

    int srow = t >> 2;
    int qc   = (t & 3) * 16;
    int gr = rb + srow;
    int sb = gr >> 11, ss = gr & 2047;
    const float* aSrc = seq + ((size_t)ss * BATCH + sb) * DIM + qc;
    const float* bSrc = wv + (size_t)(cb + srow) * DIM + qc;

    for (int k0 = 0; k0 < DIM; k0 += 64) {
        if (BF16A) {
            int dcol = k0 + qc;
            const unsigned short* p = seqb
                + ((size_t)(sb * 128 + (ss >> 4)) * 16 + (dcol >> 5)) * 512
                + (ss & 15) * 32 + (dcol & 31);
            *reinterpret_cast<u32x4*>(&Asm[srow][qc])     = *reinterpret_cast<const u32x4*>(p);
            *reinterpret_cast<u32x4*>(&Asm[srow][qc + 8]) = *reinterpret_cast<const u32x4*>(p + 8);
        } else {
            unsigned short ar[16];
            #pragma unroll
            for (int j = 0; j < 4; ++j) {
                float4 v = *reinterpret_cast<const float4*>(aSrc + k0 + j * 4);
                ar[j * 4 + 0] = f2bf(v.x); ar[j * 4 + 1] = f2bf(v.y);
                ar[j * 4 + 2] = f2bf(v.z); ar[j * 4 + 3] = f2bf(v.w);
            }
            *reinterpret_cast<u32x4*>(&Asm[srow][qc])     = *reinterpret_cast<u32x4*>(&ar[0]);
            *reinterpret_cast<u32x4*>(&Asm[srow][qc + 8]) = *reinterpret_cast<u32x4*>(&ar[8]);
        }
        {
            unsigned short br[16];
            #pragma unroll
            for (int j = 0; j < 4; ++j) {
                float4 u = *reinterpret_cast<const float4*>(bSrc + k0 + j * 4);
                br[j * 4 + 0] = f2bf(u.x); br[j * 4 + 1] = f2bf(u.y);
                br[j * 4 + 2] = f2bf(u.z); br[j * 4 + 3] = f2bf(u.w);
            }
            *reinterpret_cast<u32x4*>(&Bsm[srow][qc])     = *reinterpret_cast<u32x4*>(&br[0]);
            *reinterpret_cast<u32x4*>(&Bsm[srow][qc + 8]) = *reinterpret_cast<u32x4*>(&br[8]);
        }
        __syncthreads();
        #pragma unroll
        for (int kf = 0; kf < 2; ++kf) {
            bf16x8 af[2], bfm[2];
            #pragma unroll
            for (int i = 0; i < 2; ++i)
                af[i] = ld_bf8(&Asm[mi * 32 + i * 16 + l15][kf * 32 + lh * 8]);
            #pragma unroll
            for (int j = 0; j < 2; ++j)
                bfm[j] = ld_bf8(&Bsm[ni * 32 + j * 16 + l15][kf * 32 + lh * 8]);
            #pragma unroll
            for (int i = 0; i < 2; ++i)
                #pragma unroll
                for (int j = 0; j < 2; ++j)
                    acc[i][j] = mfma16(af[i], bfm[j], acc[i][j]);
        }
        __syncthreads();
    }
    #pragma unroll
    for (int i = 0; i < 2; ++i) {
        #pragma unroll
        for (int j = 0; j < 2; ++j) {
            int gcol = cb + ni * 32 + j * 16 + l15;
            float bias = bv[gcol];
            #pragma unroll
            for (int r = 0; r < 4; ++r) {
                int grow = rb + mi * 32 + i * 16 + lh * 4 + r;
                float x = acc[i][j][r] + bias;
                int b_ = grow >> 11, s_ = grow & 2047;
                size_t off = ((size_t)(b_ * 128 + (s_ >> 4)) * 16 + (gcol >> 5)) * 512
                             + (s_ & 15) * 32 + (gcol & 31);
                val[off] = f2bf(tanhf(x));
            }
        }
    }
}

// ---------------- fused flash attention v11 ----------------
// Identical to v10 except __launch_bounds__(512, 1): loosen the allocator's
// occupancy target so qf[2][16] (128 VGPR) + o (64 AGPR) fits WITHOUT spill.
// Real occupancy is LDS-limited to 1 block/CU (2 waves/SIMD) either way.
// QK roles (qi2 x kv4): each wave reads only its 16-kv quarter of K ->
// K LDS read amp 2x. PV roles dq in 0..7 (V amp 1x). Lane-major frag LDS,
// counted vmcnt(8), defer-max THR=8 — all from R9/R10.
__global__ void __launch_bounds__(512, 1) attn_fused(
        const unsigned short* __restrict__ val, const unsigned short* __restrict__ vt,
        float* __restrict__ out) {
    extern __shared__ char smem[];
    unsigned short* Kb = (unsigned short*)smem;              // 64 frags x 1KB lane-major
    unsigned short* Vb = (unsigned short*)(smem + 65536);    // 64 frags x 1KB lane-major
    float*          Sb = (float*)(smem + 131072);            // [64][68] f32
    unsigned short* PS = (unsigned short*)(smem + 148480);   // 8 frags x 1KB + skew
    float* stm = (float*)(smem + 156928);                    // [64]
    float* stl = stm + 64;
    float* sts = stm + 128;

    const int t = threadIdx.x;
    const int w = t >> 6, l = t & 63;
    const int l15 = l & 15, lh = l >> 4;
    const int l31 = l & 31, lh1 = l >> 5;

    int wg  = blockIdx.x;
    int swz = (wg & 7) * 64 + (wg >> 3);     // XCD-chunked, bijective (512 = 8*64)
    int b   = swz >> 5;
    int qb  = (swz & 31) * 64;

    const int qi2 = w >> 2, kv4 = w & 3;     // QK: S[qi2*32..+32][kv4*16..+16]
    const int dq = w;                        // PV: O[64q][dq*64..+64]

    const unsigned short* valb = val + (size_t)b * 128 * 16 * 512;
    const unsigned short* vtb  = vt  + (size_t)b * 128 * 16 * 512;

    if (t < 64) { stm[t] = -3.0e38f; stl[t] = 0.0f; }

    // Q fragments: 32 q rows (2 s16-tiles), 16 d32 ksteps (128 VGPR)
    bf16x8 qf[2][16];
    {
        const unsigned short* qp = valb + ((size_t)((qb >> 4) + qi2 * 2) * 16) * 512
                                   + l15 * 32 + lh * 8;
        #pragma unroll
        for (int m = 0; m < 2; ++m)
            #pragma unroll
            for (int ks = 0; ks < 16; ++ks)
                qf[m][ks] = ld_bf8(qp + (size_t)(m * 16 + ks) * 512);
    }
    f32x16 o[4] = {};   // [qg*2+dtl]: 64q x 64d

    // Kb frag (g,ks): lane l holds K[kv = g*16 + (l&15)][d = ks*32 + (l>>4)*8 ..+8]
    auto dmaK = [&](int kt) {
        #pragma unroll
        for (int i = 0; i < 8; ++i) {
            int idx = i * 8 + w, g = idx >> 4, ks = idx & 15;
            gload16(valb + ((size_t)(kt * 4 + g) * 16 + ks) * 512 + l15 * 32 + lh * 8,
                    Kb + idx * 512);
        }
    };
    // Vb frag (ks,dt): lane l holds V[kv = ks*16 + (l>>5)*8 ..+8][d = dt*32 + (l&31)]
    auto dmaV = [&](int kt) {
        #pragma unroll
        for (int i = 0; i < 8; ++i) {
            int idx = i * 8 + w, ks = idx >> 4, dt = idx & 15;
            gload16(vtb + ((size_t)(kt * 4 + ks) * 16 + dt) * 512 + l31 * 16 + lh1 * 8,
                    Vb + idx * 512);
        }
    };

    // ---- prologue: K(0), V(0); drain everything (incl. qf loads) ----
    dmaK(0);
    dmaV(0);
    WAITV(0);
    __builtin_amdgcn_s_barrier();

    for (int kt = 0; kt < NT; ++kt) {
        // ---- phase A: QK(kt) ----
        WAITV(8);                               // retire K(kt) (V stays in flight)
        __builtin_amdgcn_s_barrier();
        {
            const unsigned short* kb = Kb + (size_t)kv4 * 16 * 512 + l * 8;
            f32x4 a0 = {}, a1 = {};
            __builtin_amdgcn_s_setprio(1);
            #pragma unroll
            for (int ks = 0; ks < 16; ++ks) {
                bf16x8 kf = ld_bf8(kb + ks * 512);
                a0 = mfma16(qf[0][ks], kf, a0);
                a1 = mfma16(qf[1][ks], kf, a1);
            }
            __builtin_amdgcn_s_setprio(0);
            #pragma unroll
            for (int r = 0; r < 4; ++r) {
                Sb[(qi2 * 32 + lh * 4 + r) * 68 + kv4 * 16 + l15]      = a0[r];
                Sb[(qi2 * 32 + 16 + lh * 4 + r) * 68 + kv4 * 16 + l15] = a1[r];
            }
        }
        waitlg0();
        __builtin_amdgcn_s_barrier();

        // ---- phase B: issue K(kt+1); softmax(kt) -> PS; retire V(kt) ----
        {
            int nk = (kt + 1 < NT) ? kt + 1 : NT - 1;
            dmaK(nk);
        }
        {
            int row = t >> 3, e = t & 7;
            const float* sp = Sb + row * 68 + e * 8;
            f32x4 x0 = *reinterpret_cast<const f32x4*>(sp);
            f32x4 x1 = *reinterpret_cast<const f32x4*>(sp + 4);
            float mt = fmaxf(fmaxf(fmaxf(x0[0], x0[1]), fmaxf(x0[2], x0[3])),
                             fmaxf(fmaxf(x1[0], x1[1]), fmaxf(x1[2], x1[3])));
            #pragma unroll
            for (int m = 1; m <= 4; m <<= 1) mt = fmaxf(mt, __shfl_xor(mt, m, 64));
            float m_old = stm[row];
            float m_new = (mt > m_old + 8.0f) ? mt : m_old;    // defer-max THR=8
            float e0 = __expf(x0[0] - m_new), e1 = __expf(x0[1] - m_new);
            float e2 = __expf(x0[2] - m_new), e3 = __expf(x0[3] - m_new);
            float e4 = __expf(x1[0] - m_new), e5 = __expf(x1[1] - m_new);
            float e6 = __expf(x1[2] - m_new), e7 = __expf(x1[3] - m_new);
            float lt = ((e0 + e1) + (e2 + e3)) + ((e4 + e5) + (e6 + e7));
            #pragma unroll
            for (int m = 1; m <= 4; m <<= 1) lt += __shfl_xor(lt, m, 64);
            u32x4 pk;
            pk[0] = (unsigned)f2bf(e0) | ((unsigned)f2bf(e1) << 16);
            pk[1] = (unsigned)f2bf(e2) | ((unsigned)f2bf(e3) << 16);
            pk[2] = (unsigned)f2bf(e4) | ((unsigned)f2bf(e5) << 16);
            pk[3] = (unsigned)f2bf(e6) | ((unsigned)f2bf(e7) << 16);
            // PS frag (qg=row>>5, ks=e>>1), slot = (e&1)*32 + (row&31), skew ks*8
            int ks = e >> 1, qg = row >> 5;
            unsigned short* pdst = PS + ((qg * 4 + ks) * 512 + ks * 8)
                                   + ((e & 1) * 32 + (row & 31)) * 8;
            *reinterpret_cast<u32x4*>(pdst) = pk;
            if (e == 0) {
                float alpha = (m_new == m_old) ? 1.0f : __expf(m_old - m_new);
                sts[row] = alpha;
                stm[row] = m_new;
                stl[row] = stl[row] * alpha + lt;
            }
        }
        waitlg0();
        WAITV(8);                               // retire V(kt) (K(kt+1) stays)
        __builtin_amdgcn_s_barrier();

        // ---- phase C: rescale O + PV(kt) ----
        {
            f32x4 al[2][4];
            bool need = false;
            #pragma unroll
            for (int qg = 0; qg < 2; ++qg)
                #pragma unroll
                for (int c = 0; c < 4; ++c) {
                    al[qg][c] = *reinterpret_cast<const f32x4*>(
                        sts + qg * 32 + 4 * lh1 + 8 * c);
                    #pragma unroll
                    for (int j = 0; j < 4; ++j) need = need || (al[qg][c][j] != 1.0f);
                }
            if (__any((int)need)) {
                #pragma unroll
                for (int qg = 0; qg < 2; ++qg)
                    #pragma unroll
                    for (int dtl = 0; dtl < 2; ++dtl)
                        #pragma unroll
                        for (int rr = 0; rr < 16; ++rr)
                            o[qg * 2 + dtl][rr] *= al[qg][rr >> 2][rr & 3];
            }
            __builtin_amdgcn_s_setprio(1);
            #pragma unroll
            for (int ks = 0; ks < 4; ++ks) {
                bf16x8 pa0 = ld_bf8(PS + ((0 + ks) * 512 + ks * 8) + l * 8);
                bf16x8 pa1 = ld_bf8(PS + ((4 + ks) * 512 + ks * 8) + l * 8);
                #pragma unroll
                for (int dtl = 0; dtl < 2; ++dtl) {
                    bf16x8 vf = ld_bf8(Vb + (size_t)(ks * 16 + dq * 2 + dtl) * 512 + l * 8);
                    o[0 + dtl] = mfma32(pa0, vf, o[0 + dtl]);
                    o[2 + dtl] = mfma32(pa1, vf, o[2 + dtl]);
                }
            }
            __builtin_amdgcn_s_setprio(0);
        }
        waitlg0();
        __builtin_amdgcn_s_barrier();           // all PV reads of V(kt) done
        {
            int nv = (kt + 1 < NT) ? kt + 1 : NT - 1;
            dmaV(nv);                           // safe: after barrier
        }
    }

    // ---- epilogue ----
    #pragma unroll
    for (int qg = 0; qg < 2; ++qg) {
        f32x4 li[4];
        #pragma unroll
        for (int c = 0; c < 4; ++c) {
            f32x4 lv = *reinterpret_cast<const f32x4*>(stl + qg * 32 + 4 * lh1 + 8 * c);
            #pragma unroll
            for (int j = 0; j < 4; ++j) li[c][j] = 1.0f / lv[j];
        }
        #pragma unroll
        for (int dtl = 0; dtl < 2; ++dtl) {
            int col = dq * 64 + dtl * 32 + l31;
            #pragma unroll
            for (int rr = 0; rr < 16; ++rr) {
                int cr  = (rr & 3) + 8 * (rr >> 2) + 4 * lh1;
                int row = qb + qg * 32 + cr;
                out[(size_t)row * (BATCH * DIM) + (size_t)b * DIM + col] =
                    o[qg * 2 + dtl][rr] * li[rr >> 2][rr & 3];
            }
        }
    }
}

extern "C" void kernel_launch(void* const* d_in, const int* in_sizes, int n_in,
                              void* d_out, int out_size, void* d_ws, size_t ws_size,
                              hipStream_t stream) {
    const float* seq = (const float*)d_in[0];   // [S][B][D] f32
    const float* wv  = (const float*)d_in[1];   // [D][D] f32
    const float* bv  = (const float*)d_in[2];   // [D] f32
    float* outp = (float*)d_out;                // [S][B][D] f32

    unsigned short* wsVal  = (unsigned short*)d_ws;                         // 32 MB
    unsigned short* wsVt   = (unsigned short*)((char*)d_ws + 33554432);     // 32 MB
    unsigned short* wsSeqb = (unsigned short*)((char*)d_ws + 67108864);     // 32 MB

    bool fused = ws_size >= 100663296ull;   // need 96 MB for seqb path
    if (fused) {
        pack_seq<<<dim3(S_LEN / 32, DIM / 32, BATCH), dim3(256), 0, stream>>>(
            seq, wsSeqb, wsVt);
        gemm_value<true><<<dim3(BATCH * S_LEN / 64, DIM / 64), dim3(256), 0, stream>>>(
            seq, wsSeqb, wv, bv, wsVal);
    } else {
        pack_vt<<<dim3(S_LEN / 32, DIM / 32, BATCH), dim3(256), 0, stream>>>(seq, wsVt);
        gemm_value<false><<<dim3(BATCH * S_LEN / 64, DIM / 64), dim3(256), 0, stream>>>(
            seq, nullptr, wv, bv, wsVal);
    }
    attn_fused<<<dim3(512), dim3(512), 157696, stream>>>(wsVal, wsVt, outp);
}

// Round 12
// 268.585 us; speedup vs baseline: 1.6655x; 1.6616x over previous
//
#include <hip/hip_runtime.h>
#include <hip/hip_fp8.h>

#define S_LEN 2048
#define BATCH 16
#define DIM   512
#define KVB   64
#define NT    (S_LEN / KVB)   // 32

typedef __bf16 bf16x8 __attribute__((ext_vector_type(8)));
typedef float  f32x4  __attribute__((ext_vector_type(4)));
typedef float  f32x16 __attribute__((ext_vector_type(16)));
typedef unsigned int u32x4 __attribute__((ext_vector_type(4)));
typedef long long llx2 __attribute__((ext_vector_type(2)));

static __device__ __forceinline__ unsigned short f2bf(float f) {
    __bf16 h = (__bf16)f;
    return __builtin_bit_cast(unsigned short, h);
}
static __device__ __forceinline__ unsigned char f2fp8(float f) {
    __hip_fp8_e4m3 h(f);
    return h.__x;
}
static __device__ __forceinline__ bf16x8 ld_bf8(const unsigned short* p) {
    u32x4 v = *reinterpret_cast<const u32x4*>(p);
    return __builtin_bit_cast(bf16x8, v);
}
static __device__ __forceinline__ f32x4 mfma16(bf16x8 a, bf16x8 b, f32x4 c) {
    return __builtin_amdgcn_mfma_f32_16x16x32_bf16(a, b, c, 0, 0, 0);
}
static __device__ __forceinline__ f32x4 mfma8(long long a, long long b, f32x4 c) {
    return __builtin_amdgcn_mfma_f32_16x16x32_fp8_fp8(a, b, c, 0, 0, 0);
}
static __device__ __forceinline__ f32x16 mfma32(bf16x8 a, bf16x8 b, f32x16 c) {
    return __builtin_amdgcn_mfma_f32_32x32x16_bf16(a, b, c, 0, 0, 0);
}
static __device__ __forceinline__ void gload16(const void* g, void* l) {
    __builtin_amdgcn_global_load_lds(
        (const __attribute__((address_space(1))) unsigned int*)g,
        (__attribute__((address_space(3))) unsigned int*)l, 16, 0, 0);
}
#define WAITV(N) do { asm volatile("s_waitcnt vmcnt(" #N ")" ::: "memory"); \
                      __builtin_amdgcn_sched_barrier(0); } while (0)
static __device__ __forceinline__ void waitlg0() {
    asm volatile("s_waitcnt lgkmcnt(0)" ::: "memory");
    __builtin_amdgcn_sched_barrier(0);
}

// ---- pack_seq: seq [S][B][D] f32 -> seqb frag tiles [B][S/16][D/32][16][32] (bf16)
//                                  -> vt2  frag tiles [B][S/16][D/32][32][16] (bf16)
__global__ void pack_seq(const float* __restrict__ seq, unsigned short* __restrict__ seqb,
                         unsigned short* __restrict__ vt) {
    __shared__ float tile[32][33];
    int b  = blockIdx.z;
    int d0 = blockIdx.y * 32;
    int s0 = blockIdx.x * 32;
    int t  = threadIdx.x;
    {
        int sl = t >> 3, c4 = (t & 7) * 4;
        float4 v = *reinterpret_cast<const float4*>(
            seq + (size_t)(s0 + sl) * (BATCH * DIM) + (size_t)b * DIM + d0 + c4);
        tile[sl][c4 + 0] = v.x; tile[sl][c4 + 1] = v.y;
        tile[sl][c4 + 2] = v.z; tile[sl][c4 + 3] = v.w;
        uint2 r;
        r.x = (unsigned)f2bf(v.x) | ((unsigned)f2bf(v.y) << 16);
        r.y = (unsigned)f2bf(v.z) | ((unsigned)f2bf(v.w) << 16);
        int s = s0 + sl, d = d0 + c4;
        size_t off = ((size_t)(b * 128 + (s >> 4)) * 16 + (d >> 5)) * 512
                     + (s & 15) * 32 + (d & 31);
        *reinterpret_cast<uint2*>(seqb + off) = r;
    }
    __syncthreads();
    {
        int dl = t >> 3, s4 = (t & 7) * 4;
        uint2 r;
        r.x = (unsigned)f2bf(tile[s4 + 0][dl]) | ((unsigned)f2bf(tile[s4 + 1][dl]) << 16);
        r.y = (unsigned)f2bf(tile[s4 + 2][dl]) | ((unsigned)f2bf(tile[s4 + 3][dl]) << 16);
        int d = d0 + dl, s = s0 + s4;
        size_t off = ((size_t)(b * 128 + (s >> 4)) * 16 + (d >> 5)) * 512
                     + (d & 31) * 16 + (s & 15);
        *reinterpret_cast<uint2*>(vt + off) = r;
    }
}

// ---- fallback pack (vt2 only, when ws too small for seqb) ----
__global__ void pack_vt(const float* __restrict__ seq, unsigned short* __restrict__ vt) {
    __shared__ float tile[32][33];
    int b  = blockIdx.z;
    int d0 = blockIdx.y * 32;
    int s0 = blockIdx.x * 32;
    int t  = threadIdx.x;
    {
        int sl = t >> 3, c4 = (t & 7) * 4;
        float4 v = *reinterpret_cast<const float4*>(
            seq + (size_t)(s0 + sl) * (BATCH * DIM) + (size_t)b * DIM + d0 + c4);
        tile[sl][c4 + 0] = v.x; tile[sl][c4 + 1] = v.y;
        tile[sl][c4 + 2] = v.z; tile[sl][c4 + 3] = v.w;
    }
    __syncthreads();
    {
        int dl = t >> 3, s4 = (t & 7) * 4;
        uint2 r;
        r.x = (unsigned)f2bf(tile[s4 + 0][dl]) | ((unsigned)f2bf(tile[s4 + 1][dl]) << 16);
        r.y = (unsigned)f2bf(tile[s4 + 2][dl]) | ((unsigned)f2bf(tile[s4 + 3][dl]) << 16);
        int d = d0 + dl, s = s0 + s4;
        size_t off = ((size_t)(b * 128 + (s >> 4)) * 16 + (d >> 5)) * 512
                     + (d & 31) * 16 + (s & 15);
        *reinterpret_cast<uint2*>(vt + off) = r;
    }
}

// -------- value = tanh(seq_in @ Wv^T + bv) -> FP8 e4m3 interleaved tiles --------
// val8 layout: [B][S/16][D/64] 1KB tiles; row s&15 (64B); byte p for in-tile k':
// p = ((k'&31)>>3)*16 + (k'>>5)*8 + (k'&7)   (even/odd 32-k frag pair interleave)
template <bool BF16A>
__global__ void __launch_bounds__(256) gemm_value(
        const float* __restrict__ seq, const unsigned short* __restrict__ seqb,
        const float* __restrict__ wv, const float* __restrict__ bv,
        unsigned char* __restrict__ val8) {
    __shared__ unsigned short Asm[64][72];
    __shared__ unsigned short Bsm[64][72];
    int t  = threadIdx.x;
    int rb = blockIdx.x * 64;
    int cb = blockIdx.y * 64;
    int w = t >> 6, l = t & 63;
    int mi = w >> 1, ni = w & 1;
    int l15 = l & 15, lh = l >> 4;
    f32x4 acc[2][2] = {};

    int srow = t >> 2;
    int qc   = (t & 3) * 16;
    int gr = rb + srow;
    int sb = gr >> 11, ss = gr & 2047;
    const float* aSrc = seq + ((size_t)ss * BATCH + sb) * DIM + qc;
    const float* bSrc = wv + (size_t)(cb + srow) * DIM + qc;

    for (int k0 = 0; k0 < DIM; k0 += 64) {
        if (BF16A) {
            int dcol = k0 + qc;
            const unsigned short* p = seqb
                + ((size_t)(sb * 128 + (ss >> 4)) * 16 + (dcol >> 5)) * 512
                + (ss & 15) * 32 + (dcol & 31);
            *reinterpret_cast<u32x4*>(&Asm[srow][qc])     = *reinterpret_cast<const u32x4*>(p);
            *reinterpret_cast<u32x4*>(&Asm[srow][qc + 8]) = *reinterpret_cast<const u32x4*>(p + 8);
        } else {
            unsigned short ar[16];
            #pragma unroll
            for (int j = 0; j < 4; ++j) {
                float4 v = *reinterpret_cast<const float4*>(aSrc + k0 + j * 4);
                ar[j * 4 + 0] = f2bf(v.x); ar[j * 4 + 1] = f2bf(v.y);
                ar[j * 4 + 2] = f2bf(v.z); ar[j * 4 + 3] = f2bf(v.w);
            }
            *reinterpret_cast<u32x4*>(&Asm[srow][qc])     = *reinterpret_cast<u32x4*>(&ar[0]);
            *reinterpret_cast<u32x4*>(&Asm[srow][qc + 8]) = *reinterpret_cast<u32x4*>(&ar[8]);
        }
        {
            unsigned short br[16];
            #pragma unroll
            for (int j = 0; j < 4; ++j) {
                float4 u = *reinterpret_cast<const float4*>(bSrc + k0 + j * 4);
                br[j * 4 + 0] = f2bf(u.x); br[j * 4 + 1] = f2bf(u.y);
                br[j * 4 + 2] = f2bf(u.z); br[j * 4 + 3] = f2bf(u.w);
            }
            *reinterpret_cast<u32x4*>(&Bsm[srow][qc])     = *reinterpret_cast<u32x4*>(&br[0]);
            *reinterpret_cast<u32x4*>(&Bsm[srow][qc + 8]) = *reinterpret_cast<u32x4*>(&br[8]);
        }
        __syncthreads();
        #pragma unroll
        for (int kf = 0; kf < 2; ++kf) {
            bf16x8 af[2], bfm[2];
            #pragma unroll
            for (int i = 0; i < 2; ++i)
                af[i] = ld_bf8(&Asm[mi * 32 + i * 16 + l15][kf * 32 + lh * 8]);
            #pragma unroll
            for (int j = 0; j < 2; ++j)
                bfm[j] = ld_bf8(&Bsm[ni * 32 + j * 16 + l15][kf * 32 + lh * 8]);
            #pragma unroll
            for (int i = 0; i < 2; ++i)
                #pragma unroll
                for (int j = 0; j < 2; ++j)
                    acc[i][j] = mfma16(af[i], bfm[j], acc[i][j]);
        }
        __syncthreads();
    }
    #pragma unroll
    for (int i = 0; i < 2; ++i) {
        #pragma unroll
        for (int j = 0; j < 2; ++j) {
            int gcol = cb + ni * 32 + j * 16 + l15;
            float bias = bv[gcol];
            int kp = gcol & 63;
            int p  = ((kp & 31) >> 3) * 16 + (kp >> 5) * 8 + (kp & 7);
            #pragma unroll
            for (int r = 0; r < 4; ++r) {
                int grow = rb + mi * 32 + i * 16 + lh * 4 + r;
                float x = acc[i][j][r] + bias;
                int b_ = grow >> 11, s_ = grow & 2047;
                size_t off = ((size_t)(b_ * 128 + (s_ >> 4)) * 8 + (gcol >> 6)) * 1024
                             + (s_ & 15) * 64 + p;
                val8[off] = f2fp8(tanhf(x));
            }
        }
    }
}

// ---------------- fused flash attention v12 ----------------
// R9 structure with FP8 Q/K: QK uses mfma_f32_16x16x32_fp8_fp8; K tile in LDS
// shrinks 64->32KB, K LDS read 256->128KB/iter (-29% total LDS bytes); Q = 32
// VGPR. Frag pairs (even/odd 32-k) interleaved in 16B lane units so DMA writes
// and ds_read_b128 stay dense 1KB. V/P stay bf16. Counted vmcnt: A-top (8)
// retires K [dmaK=4/thread], B-end (4) retires V [dmaV=8/thread].
__global__ void __launch_bounds__(512, 2) attn_fused(
        const unsigned char* __restrict__ val8, const unsigned short* __restrict__ vt,
        float* __restrict__ out) {
    extern __shared__ char smem[];
    unsigned char*  Kb = (unsigned char*)smem;               // 32 frag-pairs x 1KB fp8
    unsigned short* Vb = (unsigned short*)(smem + 32768);    // 64 frags x 1KB bf16
    float*          Sb = (float*)(smem + 98304);             // [64][68] f32
    unsigned short* PS = (unsigned short*)(smem + 115712);   // 8 frags x 1KB + skew
    float* stm = (float*)(smem + 124160);                    // [64]
    float* stl = stm + 64;
    float* sts = stm + 128;

    const int t = threadIdx.x;
    const int w = t >> 6, l = t & 63;
    const int l15 = l & 15, lh = l >> 4;
    const int l31 = l & 31, lh1 = l >> 5;

    int wg  = blockIdx.x;
    int swz = (wg & 7) * 64 + (wg >> 3);     // XCD-chunked, bijective (512 = 8*64)
    int b   = swz >> 5;
    int qb  = (swz & 31) * 64;

    const int qi = w & 3, khi = w >> 2;      // QK: S[qi*16..+16][khi*32..+32]
    const int dq = w;                        // PV: O[64q][dq*64..+64]

    const unsigned char*  valb = val8 + (size_t)b * 128 * 8 * 1024;
    const unsigned short* vtb  = vt   + (size_t)b * 128 * 16 * 512;

    if (t < 64) { stm[t] = -3.0e38f; stl[t] = 0.0f; }

    // Q fragments fp8: rows qb+qi*16+l15, 8 d64 super-steps (32 VGPR)
    long long qe[8], qo[8];
    {
        const unsigned char* qp = valb + (size_t)((qb >> 4) + qi) * 8 * 1024
                                  + l15 * 64 + lh * 16;
        #pragma unroll
        for (int s = 0; s < 8; ++s) {
            u32x4 v = *reinterpret_cast<const u32x4*>(qp + s * 1024);
            llx2 pr = __builtin_bit_cast(llx2, v);
            qe[s] = pr[0]; qo[s] = pr[1];
        }
    }
    f32x16 o[4] = {};   // [qg*2+dtl]: 64q x 64d

    // Kb frag-pair (g,s): lane l holds K[kv=g*16+(l&15)] bytes 16 @ d-pair s
    auto dmaK = [&](int kt) {
        #pragma unroll
        for (int i = 0; i < 4; ++i) {
            int idx = i * 8 + w, g = idx >> 3, s = idx & 7;
            gload16(valb + ((size_t)(kt * 4 + g) * 8 + s) * 1024 + l15 * 64 + lh * 16,
                    Kb + idx * 1024);
        }
    };
    // Vb frag (ks,dt): lane l holds V[kv = ks*16 + (l>>5)*8 ..+8][d = dt*32 + (l&31)]
    auto dmaV = [&](int kt) {
        #pragma unroll
        for (int i = 0; i < 8; ++i) {
            int idx = i * 8 + w, ks = idx >> 4, dt = idx & 15;
            gload16(vtb + ((size_t)(kt * 4 + ks) * 16 + dt) * 512 + l31 * 16 + lh1 * 8,
                    Vb + idx * 512);
        }
    };

    // ---- prologue: K(0), V(0); drain everything (incl. qf loads) ----
    dmaK(0);
    dmaV(0);
    WAITV(0);
    __builtin_amdgcn_s_barrier();

    for (int kt = 0; kt < NT; ++kt) {
        // ---- phase A: QK(kt), fp8 ----
        WAITV(8);                               // retire K(kt) (V(kt) 8 stay)
        __builtin_amdgcn_s_barrier();
        {
            const unsigned char* kb0 = Kb + (2 * khi) * 8192 + l * 16;
            const unsigned char* kb1 = kb0 + 8192;
            f32x4 a00 = {}, a01 = {}, a10 = {}, a11 = {};
            __builtin_amdgcn_s_setprio(1);
            #pragma unroll
            for (int s = 0; s < 8; ++s) {
                u32x4 k0 = *reinterpret_cast<const u32x4*>(kb0 + s * 1024);
                u32x4 k1 = *reinterpret_cast<const u32x4*>(kb1 + s * 1024);
                llx2 p0 = __builtin_bit_cast(llx2, k0);
                llx2 p1 = __builtin_bit_cast(llx2, k1);
                a00 = mfma8(qe[s], p0[0], a00);
                a10 = mfma8(qe[s], p1[0], a10);
                a01 = mfma8(qo[s], p0[1], a01);
                a11 = mfma8(qo[s], p1[1], a11);
            }
            __builtin_amdgcn_s_setprio(0);
            f32x4 s0 = a00 + a01, s1 = a10 + a11;
            #pragma unroll
            for (int r = 0; r < 4; ++r) {
                Sb[(qi * 16 + lh * 4 + r) * 68 + khi * 32 + l15]      = s0[r];
                Sb[(qi * 16 + lh * 4 + r) * 68 + khi * 32 + 16 + l15] = s1[r];
            }
        }
        waitlg0();
        __builtin_amdgcn_s_barrier();

        // ---- phase B: issue K(kt+1); softmax(kt) -> PS; retire V(kt) ----
        {
            int nk = (kt + 1 < NT) ? kt + 1 : NT - 1;
            dmaK(nk);
        }
        {
            int row = t >> 3, e = t & 7;
            const float* sp = Sb + row * 68 + e * 8;
            f32x4 x0 = *reinterpret_cast<const f32x4*>(sp);
            f32x4 x1 = *reinterpret_cast<const f32x4*>(sp + 4);
            float mt = fmaxf(fmaxf(fmaxf(x0[0], x0[1]), fmaxf(x0[2], x0[3])),
                             fmaxf(fmaxf(x1[0], x1[1]), fmaxf(x1[2], x1[3])));
            #pragma unroll
            for (int m = 1; m <= 4; m <<= 1) mt = fmaxf(mt, __shfl_xor(mt, m, 64));
            float m_old = stm[row];
            float m_new = (mt > m_old + 8.0f) ? mt : m_old;    // defer-max THR=8
            float e0 = __expf(x0[0] - m_new), e1 = __expf(x0[1] - m_new);
            float e2 = __expf(x0[2] - m_new), e3 = __expf(x0[3] - m_new);
            float e4 = __expf(x1[0] - m_new), e5 = __expf(x1[1] - m_new);
            float e6 = __expf(x1[2] - m_new), e7 = __expf(x1[3] - m_new);
            float lt = ((e0 + e1) + (e2 + e3)) + ((e4 + e5) + (e6 + e7));
            #pragma unroll
            for (int m = 1; m <= 4; m <<= 1) lt += __shfl_xor(lt, m, 64);
            u32x4 pk;
            pk[0] = (unsigned)f2bf(e0) | ((unsigned)f2bf(e1) << 16);
            pk[1] = (unsigned)f2bf(e2) | ((unsigned)f2bf(e3) << 16);
            pk[2] = (unsigned)f2bf(e4) | ((unsigned)f2bf(e5) << 16);
            pk[3] = (unsigned)f2bf(e6) | ((unsigned)f2bf(e7) << 16);
            int ks = e >> 1, qg = row >> 5;
            unsigned short* pdst = PS + ((qg * 4 + ks) * 512 + ks * 8)
                                   + ((e & 1) * 32 + (row & 31)) * 8;
            *reinterpret_cast<u32x4*>(pdst) = pk;
            if (e == 0) {
                float alpha = (m_new == m_old) ? 1.0f : __expf(m_old - m_new);
                sts[row] = alpha;
                stm[row] = m_new;
                stl[row] = stl[row] * alpha + lt;
            }
        }
        waitlg0();
        WAITV(4);                               // retire V(kt) (K(kt+1) 4 stay)
        __builtin_amdgcn_s_barrier();

        // ---- phase C: rescale O + PV(kt) ----
        {
            f32x4 al[2][4];
            bool need = false;
            #pragma unroll
            for (int qg = 0; qg < 2; ++qg)
                #pragma unroll
                for (int c = 0; c < 4; ++c) {
                    al[qg][c] = *reinterpret_cast<const f32x4*>(
                        sts + qg * 32 + 4 * lh1 + 8 * c);
                    #pragma unroll
                    for (int j = 0; j < 4; ++j) need = need || (al[qg][c][j] != 1.0f);
                }
            if (__any((int)need)) {
                #pragma unroll
                for (int qg = 0; qg < 2; ++qg)
                    #pragma unroll
                    for (int dtl = 0; dtl < 2; ++dtl)
                        #pragma unroll
                        for (int rr = 0; rr < 16; ++rr)
                            o[qg * 2 + dtl][rr] *= al[qg][rr >> 2][rr & 3];
            }
            __builtin_amdgcn_s_setprio(1);
            #pragma unroll
            for (int ks = 0; ks < 4; ++ks) {
                bf16x8 pa0 = ld_bf8(PS + ((0 + ks) * 512 + ks * 8) + l * 8);
                bf16x8 pa1 = ld_bf8(PS + ((4 + ks) * 512 + ks * 8) + l * 8);
                #pragma unroll
                for (int dtl = 0; dtl < 2; ++dtl) {
                    bf16x8 vf = ld_bf8(Vb + (size_t)(ks * 16 + dq * 2 + dtl) * 512 + l * 8);
                    o[0 + dtl] = mfma32(pa0, vf, o[0 + dtl]);
                    o[2 + dtl] = mfma32(pa1, vf, o[2 + dtl]);
                }
            }
            __builtin_amdgcn_s_setprio(0);
        }
        waitlg0();
        __builtin_amdgcn_s_barrier();           // all PV reads of V(kt) done
        {
            int nv = (kt + 1 < NT) ? kt + 1 : NT - 1;
            dmaV(nv);                           // safe: after barrier
        }
    }

    // ---- epilogue ----
    #pragma unroll
    for (int qg = 0; qg < 2; ++qg) {
        f32x4 li[4];
        #pragma unroll
        for (int c = 0; c < 4; ++c) {
            f32x4 lv = *reinterpret_cast<const f32x4*>(stl + qg * 32 + 4 * lh1 + 8 * c);
            #pragma unroll
            for (int j = 0; j < 4; ++j) li[c][j] = 1.0f / lv[j];
        }
        #pragma unroll
        for (int dtl = 0; dtl < 2; ++dtl) {
            int col = dq * 64 + dtl * 32 + l31;
            #pragma unroll
            for (int rr = 0; rr < 16; ++rr) {
                int cr  = (rr & 3) + 8 * (rr >> 2) + 4 * lh1;
                int row = qb + qg * 32 + cr;
                out[(size_t)row * (BATCH * DIM) + (size_t)b * DIM + col] =
                    o[qg * 2 + dtl][rr] * li[rr >> 2][rr & 3];
            }
        }
    }
}

extern "C" void kernel_launch(void* const* d_in, const int* in_sizes, int n_in,
                              void* d_out, int out_size, void* d_ws, size_t ws_size,
                              hipStream_t stream) {
    const float* seq = (const float*)d_in[0];   // [S][B][D] f32
    const float* wv  = (const float*)d_in[1];   // [D][D] f32
    const float* bv  = (const float*)d_in[2];   // [D] f32
    float* outp = (float*)d_out;                // [S][B][D] f32

    unsigned char*  wsVal8 = (unsigned char*)d_ws;                          // 16 MB fp8
    unsigned short* wsVt   = (unsigned short*)((char*)d_ws + 33554432);     // 32 MB
    unsigned short* wsSeqb = (unsigned short*)((char*)d_ws + 67108864);     // 32 MB

    bool fused = ws_size >= 100663296ull;   // need 96 MB for seqb path
    if (fused) {
        pack_seq<<<dim3(S_LEN / 32, DIM / 32, BATCH), dim3(256), 0, stream>>>(
            seq, wsSeqb, wsVt);
        gemm_value<true><<<dim3(BATCH * S_LEN / 64, DIM / 64), dim3(256), 0, stream>>>(
            seq, wsSeqb, wv, bv, wsVal8);
    } else {
        pack_vt<<<dim3(S_LEN / 32, DIM / 32, BATCH), dim3(256), 0, stream>>>(seq, wsVt);
        gemm_value<false><<<dim3(BATCH * S_LEN / 64, DIM / 64), dim3(256), 0, stream>>>(
            seq, nullptr, wv, bv, wsVal8);
    }
    attn_fused<<<dim3(512), dim3(512), 124928, stream>>>(wsVal8, wsVt, outp);
}